// Round 2
// baseline (2281.948 us; speedup 1.0000x reference)
//
#include <hip/hip_runtime.h>
#include <hip/hip_bf16.h>

// Problem constants
#define B_   32
#define TP_  256
#define TQ_  64
#define D_   256
#define H_   128
#define G4_  512   // 4*H

// ---------- helpers ----------
__device__ __forceinline__ float lanebc(float v, int l) {
  // broadcast lane l of v to all lanes (uniform l)
  return __int_as_float(__builtin_amdgcn_readlane(__float_as_int(v), l));
}
__device__ __forceinline__ float fast_tanh(float x) {
  x = fminf(fmaxf(x, -20.f), 20.f);
  float e = __expf(2.f * x);
  return __fdividef(e - 1.f, e + 1.f);
}
__device__ __forceinline__ float fast_sig(float x) {
  return __fdividef(1.f, 1.f + __expf(-x));
}

// ---------- tiled fp32 GEMM: C[M,N] = A[M,K] @ B[K,N] (+ bias[N]) ----------
// 128x128 tile, BK=8, 256 threads, 8x8 micro-tile.
// Requires M%128==0, N%128==0, K%8==0 (all call sites satisfy this).
__global__ __launch_bounds__(256)
void gemm_bias_kernel(const float* __restrict__ A, const float* __restrict__ Bm,
                      const float* __restrict__ bias, float* __restrict__ C,
                      int M, int N, int K)
{
  __shared__ float As[8][132];   // [k][m] transposed, +4 pad
  __shared__ float Bs[8][132];   // [k][n], +4 pad
  const int tid = threadIdx.x;
  const int tx = tid & 15;        // col group: cols tx*8 .. tx*8+7
  const int ty = tid >> 4;        // row group: rows ty*8 .. ty*8+7
  const int m0 = blockIdx.x * 128, n0 = blockIdx.y * 128;

  float acc[8][8];
#pragma unroll
  for (int i = 0; i < 8; ++i)
#pragma unroll
    for (int j = 0; j < 8; ++j) acc[i][j] = 0.f;

  // loaders
  const int am = tid >> 1, ak = (tid & 1) * 4;    // A: row am, k-offset ak..ak+3
  const int bk = tid >> 5, bn = (tid & 31) * 4;   // B: k-row bk, cols bn..bn+3
  const float* Ap = A + (size_t)(m0 + am) * K + ak;
  const float* Bp = Bm + (size_t)bk * N + n0 + bn;

  for (int kt = 0; kt < K; kt += 8) {
    float4 a4 = *(const float4*)(Ap + kt);
    float4 b4 = *(const float4*)(Bp + (size_t)kt * N);
    __syncthreads();  // protect LDS from previous iteration's readers
    As[ak + 0][am] = a4.x; As[ak + 1][am] = a4.y;
    As[ak + 2][am] = a4.z; As[ak + 3][am] = a4.w;
    *(float4*)&Bs[bk][bn] = b4;
    __syncthreads();
#pragma unroll
    for (int k = 0; k < 8; ++k) {
      float4 a0 = *(const float4*)&As[k][ty * 8];
      float4 a1 = *(const float4*)&As[k][ty * 8 + 4];
      float4 b0 = *(const float4*)&Bs[k][tx * 8];
      float4 b1 = *(const float4*)&Bs[k][tx * 8 + 4];
      float av[8] = {a0.x, a0.y, a0.z, a0.w, a1.x, a1.y, a1.z, a1.w};
      float bv[8] = {b0.x, b0.y, b0.z, b0.w, b1.x, b1.y, b1.z, b1.w};
#pragma unroll
      for (int i = 0; i < 8; ++i)
#pragma unroll
        for (int j = 0; j < 8; ++j) acc[i][j] += av[i] * bv[j];
    }
  }

  float bb[8] = {0.f, 0.f, 0.f, 0.f, 0.f, 0.f, 0.f, 0.f};
  if (bias) {
    float4 b0 = *(const float4*)&bias[n0 + tx * 8];
    float4 b1 = *(const float4*)&bias[n0 + tx * 8 + 4];
    bb[0] = b0.x; bb[1] = b0.y; bb[2] = b0.z; bb[3] = b0.w;
    bb[4] = b1.x; bb[5] = b1.y; bb[6] = b1.z; bb[7] = b1.w;
  }
#pragma unroll
  for (int i = 0; i < 8; ++i) {
    float* cp = C + (size_t)(m0 + ty * 8 + i) * N + n0 + tx * 8;
    float4 o0, o1;
    o0.x = acc[i][0] + bb[0]; o0.y = acc[i][1] + bb[1];
    o0.z = acc[i][2] + bb[2]; o0.w = acc[i][3] + bb[3];
    o1.x = acc[i][4] + bb[4]; o1.y = acc[i][5] + bb[5];
    o1.z = acc[i][6] + bb[6]; o1.w = acc[i][7] + bb[7];
    *(float4*)(cp)     = o0;
    *(float4*)(cp + 4) = o1;
  }
}

// ---------- sequential scan: one block per (batch, dir) chain ----------
// 512 threads. Precomputed: Gq, Gpx (=input_p@Wpr_x + b_pr), XW (=input_p@Wx + b_lstm),
// QZ (=input_q@Wz). Streams Wpr_h (64KB) + Wh (256KB) fp32 from L2 each step.
__global__ __launch_bounds__(512, 2)
void scan_kernel(const float* __restrict__ Gq,
                 const float* __restrict__ Gpx,
                 const float* __restrict__ XW,   // [2][B*TP*4H]
                 const float* __restrict__ QZ,   // [2][B*TQ*4H]
                 const float* __restrict__ W_pr, // (384,128)
                 const float* __restrict__ Wlf,  // (640,512)
                 const float* __restrict__ Wlb,  // (640,512)
                 const float* __restrict__ w_att,
                 const float* __restrict__ b_match,
                 const float* __restrict__ mask_p,
                 const float* __restrict__ mask_q,
                 float* __restrict__ out)        // states (B,TP,2H) then last (B,2H)
{
  const int tid  = threadIdx.x;
  const int lane = tid & 63;
  const int bch  = blockIdx.x >> 1;
  const int dir  = blockIdx.x & 1;

  __shared__ float h_s[H_], c_s[H_];
  __shared__ __align__(16) float gpr_s[H_];
  __shared__ float part_s[4][H_];
  __shared__ float a_s[TQ_];
  __shared__ __align__(16) float alpha_s[TQ_];
  __shared__ float pre_s[G4_];

  const float* Wl   = dir ? Wlb : Wlf;
  const float* Whp  = Wl + 512 * G4_ + tid;        // Wh[k][n], step k*512
  const float* Wprh = W_pr + 256 * H_;             // rows 256..383
  const float* XWd  = XW + (size_t)dir * (B_ * TP_ * G4_) + (size_t)bch * TP_ * G4_;
  const float* QZd  = QZ + (size_t)dir * (B_ * TQ_ * G4_) + (size_t)bch * TQ_ * G4_;
  const float* Gqb  = Gq + (size_t)bch * TQ_ * H_;
  const float* Gpxb = Gpx + (size_t)bch * TP_ * H_;
  const float* mpb  = mask_p + bch * TP_;

  const float bm = b_match[0];

  // QZ column tid resident in registers: qz[t'] = QZ[b,d][t'][tid]
  float qz[TQ_];
  {
    const float* q = QZd + tid;
#pragma unroll
    for (int t2 = 0; t2 < TQ_; ++t2) qz[t2] = q[t2 * G4_];
  }
  // P2 mapping: t8 = query-timestep, k8 = 16-wide j-slice
  const int t8 = tid >> 3, k8 = tid & 7;
  float gqr[16], wa[16];
  {
    const float* g = Gqb + t8 * H_ + k8 * 16;
    const float* w = w_att + k8 * 16;
#pragma unroll
    for (int i = 0; i < 16; ++i) { gqr[i] = g[i]; wa[i] = w[i]; }
  }
  float mqv = 0.f;
  if (tid < TQ_) mqv = mask_q[bch * TQ_ + tid];

  if (tid < H_) { h_s[tid] = 0.f; c_s[tid] = 0.f; }
  __syncthreads();

  const int kc = tid >> 7;        // P1: k-chunk (wave-uniform)
  const int j1 = tid & 127;       // P1: output column
  const int hbase = (kc & 1) * 32;

  for (int s = 0; s < TP_; ++s) {
    const int t = dir ? (TP_ - 1 - s) : s;

    // prefetches for this step
    float xw_v = XWd[t * G4_ + tid];
    float gpx_v = 0.f, mp = 0.f;
    if (tid < H_) { gpx_v = Gpxb[t * H_ + tid]; mp = mpb[t]; }

    // stage h for wave-broadcast (readlane)
    float h2  = h_s[lane];
    float h2b = h_s[64 + lane];

    // ---- P1: partial gpr[j] = sum_k h[k] * Wpr_h[k][j] (k split 4 ways) ----
    {
      float acc = 0.f;
      const float* wp = Wprh + kc * 32 * H_ + j1;
      float hsrc = (kc >= 2) ? h2b : h2;
#pragma unroll
      for (int kb = 0; kb < 4; ++kb) {
        float w[8];
#pragma unroll
        for (int i = 0; i < 8; ++i) w[i] = wp[(kb * 8 + i) * H_];
#pragma unroll
        for (int i = 0; i < 8; ++i) acc += lanebc(hsrc, hbase + kb * 8 + i) * w[i];
      }
      part_s[kc][j1] = acc;
    }
    __syncthreads();   // B1
    if (tid < H_) {
      gpr_s[tid] = gpx_v + part_s[0][tid] + part_s[1][tid] + part_s[2][tid] + part_s[3][tid];
    }
    __syncthreads();   // B2

    // ---- P2: a[t8] = b_match + sum_j w_att[j] * tanh(gpr[j] + Gq[t8][j]) ----
    {
      const float4* gp = (const float4*)&gpr_s[k8 * 16];
      float4 G0 = gp[0], G1 = gp[1], G2 = gp[2], G3 = gp[3];
      float gr[16] = {G0.x, G0.y, G0.z, G0.w, G1.x, G1.y, G1.z, G1.w,
                      G2.x, G2.y, G2.z, G2.w, G3.x, G3.y, G3.z, G3.w};
      float p = 0.f;
#pragma unroll
      for (int i = 0; i < 16; ++i)
        p += wa[i] * fast_tanh(gr[i] + gqr[i]);
      p += __shfl_xor(p, 1);
      p += __shfl_xor(p, 2);
      p += __shfl_xor(p, 4);
      if (k8 == 0) a_s[t8] = p + bm;
    }
    __syncthreads();   // B3

    // ---- P3: masked softmax over 64 (wave 0) ----
    if (tid < TQ_) {
      float av = a_s[tid];
      av = fminf(fmaxf(av, -15.f), 15.f) * mqv;
      float mx = av;
#pragma unroll
      for (int o = 1; o < 64; o <<= 1) mx = fmaxf(mx, __shfl_xor(mx, o));
      float e = __expf(av - mx) * mqv;
      float sm = e;
#pragma unroll
      for (int o = 1; o < 64; o <<= 1) sm += __shfl_xor(sm, o);
      alpha_s[tid] = __fdividef(e, sm + 1e-6f);
    }
    __syncthreads();   // B4

    // ---- P4: pre[n] = XW + alpha@QZ + h@Wh ----
    {
      float acc = xw_v;                 // includes b_lstm
      float av = alpha_s[lane];
#pragma unroll
      for (int t2 = 0; t2 < TQ_; ++t2) acc += lanebc(av, t2) * qz[t2];
      const float* wh = Whp;
#pragma unroll
      for (int kb = 0; kb < 8; ++kb) {
        float w[16];
#pragma unroll
        for (int i = 0; i < 16; ++i) w[i] = wh[(kb * 16 + i) * G4_];
#pragma unroll
        for (int i = 0; i < 16; ++i) {
          const int k = kb * 16 + i;
          acc += lanebc((k < 64) ? h2 : h2b, k & 63) * w[i];
        }
      }
      pre_s[tid] = acc;
    }
    __syncthreads();   // B5

    // ---- P5: LSTM pointwise + state update + output ----
    if (tid < H_) {
      float f  = pre_s[tid];
      float ig = pre_s[H_ + tid];
      float og = pre_s[2 * H_ + tid];
      float gg = pre_s[3 * H_ + tid];
      float c_old = c_s[tid], h_old = h_s[tid];
      float c1 = fast_sig(f) * c_old + fast_sig(ig) * fast_tanh(gg);
      c1 = c1 * mp + c_old * (1.f - mp);
      float h1 = fast_sig(og) * fast_tanh(c1);
      h1 = h1 * mp + h_old * (1.f - mp);
      c_s[tid] = c1;
      h_s[tid] = h1;
      out[(size_t)(bch * TP_ + t) * (2 * H_) + dir * H_ + tid] = h1 * mp;
      if (s == TP_ - 1)
        out[(size_t)B_ * TP_ * 2 * H_ + bch * (2 * H_) + dir * H_ + tid] = h1;
    }
    __syncthreads();   // B6
  }
}

// ---------- host ----------
extern "C" void kernel_launch(void* const* d_in, const int* in_sizes, int n_in,
                              void* d_out, int out_size, void* d_ws, size_t ws_size,
                              hipStream_t stream) {
  const float* input_p = (const float*)d_in[0];
  const float* mask_p  = (const float*)d_in[1];
  const float* input_q = (const float*)d_in[2];
  const float* mask_q  = (const float*)d_in[3];
  const float* W_pr    = (const float*)d_in[4];
  const float* b_pr    = (const float*)d_in[5];
  const float* W_q     = (const float*)d_in[6];
  const float* b_q     = (const float*)d_in[7];
  const float* w_att   = (const float*)d_in[8];
  const float* b_match = (const float*)d_in[9];
  const float* W_lf    = (const float*)d_in[10];
  const float* b_lf    = (const float*)d_in[11];
  const float* W_lb    = (const float*)d_in[12];
  const float* b_lb    = (const float*)d_in[13];
  float* out = (float*)d_out;
  float* ws  = (float*)d_ws;

  // workspace layout (floats)
  float* Gq  = ws;                          // 2048*128    = 262144
  float* Gpx = Gq + 262144;                 // 8192*128    = 1048576
  float* XW  = Gpx + 1048576;               // 2*8192*512  = 8388608
  float* QZ  = XW + 8388608;                // 2*2048*512  = 2097152
  // total = 11,796,480 floats (~47.2 MB)

  dim3 blk(256);
  // Gq = input_q @ W_q + b_q                       (2048,128,256)
  gemm_bias_kernel<<<dim3(2048 / 128, 128 / 128), blk, 0, stream>>>(input_q, W_q, b_q, Gq, 2048, 128, 256);
  // Gpx = input_p @ W_pr[0:256] + b_pr             (8192,128,256)
  gemm_bias_kernel<<<dim3(8192 / 128, 128 / 128), blk, 0, stream>>>(input_p, W_pr, b_pr, Gpx, 8192, 128, 256);
  // XW_d = input_p @ W_lstm_d[0:256] + b_lstm_d    (8192,512,256)
  gemm_bias_kernel<<<dim3(8192 / 128, 512 / 128), blk, 0, stream>>>(input_p, W_lf, b_lf, XW, 8192, 512, 256);
  gemm_bias_kernel<<<dim3(8192 / 128, 512 / 128), blk, 0, stream>>>(input_p, W_lb, b_lb, XW + (size_t)8192 * 512, 8192, 512, 256);
  // QZ_d = input_q @ W_lstm_d[256:512]             (2048,512,256)
  gemm_bias_kernel<<<dim3(2048 / 128, 512 / 128), blk, 0, stream>>>(input_q, W_lf + 256 * 512, nullptr, QZ, 2048, 512, 256);
  gemm_bias_kernel<<<dim3(2048 / 128, 512 / 128), blk, 0, stream>>>(input_q, W_lb + 256 * 512, nullptr, QZ + (size_t)2048 * 512, 2048, 512, 256);

  // sequential bi-directional match-LSTM scan: 64 chains (32 batch x 2 dir)
  scan_kernel<<<64, 512, 0, stream>>>(Gq, Gpx, XW, QZ, W_pr, W_lf, W_lb,
                                      w_att, b_match, mask_p, mask_q, out);
}